// Round 1
// baseline (874.846 us; speedup 1.0000x reference)
//
#include <hip/hip_runtime.h>
#include <math.h>

// ModalityRouter: logits = x @ gate_w^T  (M=32768, K=2048, N=64 experts),
// top-2 -> softmax -> gates, indices, expert load (segment_sum), top_logits.
//
// Design: expert-per-lane fp32 "GEMV-broadcast" GEMM.
//   - lane e (0..63) owns expert e; gate_w row chunk held in VGPRs.
//   - x addresses are wave-uniform -> s_load path; inner loop is pure
//     v_fmac_f32 acc, s_x, v_w (no LDS, no per-FMA vmem).
//   - 4 waves/block split K (512 each), 32 tokens/block -> grid 1024
//     (= 4 blocks/CU x 4 waves = 4 waves/SIMD).
//   - epilogue: LDS cross-wave reduce, per-token top-2 + 2-way softmax,
//     block-local load accumulation, 64 global atomics/block.

#define NE        64          // experts
#define KD        2048        // hidden dim
#define TT        32          // tokens per block
#define NWAVE     4
#define KPW       (KD / NWAVE) // 512 K per wave
#define BK        16          // k-chunk (regs) per iteration

#define M_TOTAL   32768
#define IDX_OFF   65536       // floats
#define LOAD_OFF  131072
#define TL_OFF    131136

__global__ __launch_bounds__(256, 4)
void router_kernel(const float* __restrict__ x,
                   const float* __restrict__ gw,
                   float* __restrict__ out)
{
    __shared__ float part[NWAVE][TT][NE + 2];  // +2 pad: conflict-free col reads
    __shared__ float sload[NE];

    const int tid  = threadIdx.x;
    const int wave = tid >> 6;
    const int lane = tid & 63;                 // expert id
    const long tok0 = (long)blockIdx.x * TT;

    const float* wrow = gw + (size_t)lane * KD + wave * KPW;  // per-lane expert row
    const float* xb   = x + (size_t)tok0 * KD + wave * KPW;   // wave-uniform

    float acc[TT];
#pragma unroll
    for (int t = 0; t < TT; ++t) acc[t] = 0.0f;

    // double-buffered gate_w chunk (per-lane, L2-hot after first touch)
    const float4* wp = reinterpret_cast<const float4*>(wrow);
    float4 wb[BK / 4];
#pragma unroll
    for (int j = 0; j < BK / 4; ++j) wb[j] = wp[j];

    for (int c = 0; c < KPW; c += BK) {
        float wv[BK];
#pragma unroll
        for (int j = 0; j < BK / 4; ++j) {
            wv[4 * j + 0] = wb[j].x;
            wv[4 * j + 1] = wb[j].y;
            wv[4 * j + 2] = wb[j].z;
            wv[4 * j + 3] = wb[j].w;
        }
        if (c + BK < KPW) {                    // prefetch next w chunk
            wp += BK / 4;
#pragma unroll
            for (int j = 0; j < BK / 4; ++j) wb[j] = wp[j];
        }
#pragma unroll
        for (int t = 0; t < TT; ++t) {
            const float* xr = xb + (size_t)t * KD + c;  // uniform -> s_load
#pragma unroll
            for (int j = 0; j < BK; ++j)
                acc[t] = fmaf(xr[j], wv[j], acc[t]);
        }
    }

    // cross-wave K reduction via LDS
#pragma unroll
    for (int t = 0; t < TT; ++t) part[wave][t][lane] = acc[t];
    if (tid < NE) sload[tid] = 0.0f;
    __syncthreads();

    // owner-computes: each (t,e) touched by exactly one thread
    for (int i = tid; i < TT * NE; i += 256) {
        const int t = i >> 6, e = i & 63;
        part[0][t][e] = part[0][t][e] + part[1][t][e]
                      + part[2][t][e] + part[3][t][e];
    }
    __syncthreads();

    if (tid < TT) {
        const int t = tid;
        // top-1 (strict > keeps lowest index on ties, matching lax.top_k)
        float v0 = -3.0e38f; int i0 = 0;
#pragma unroll
        for (int e = 0; e < NE; ++e) {
            const float v = part[0][t][e];
            if (v > v0) { v0 = v; i0 = e; }
        }
        // top-2 excluding i0
        float v1 = -3.0e38f; int i1 = 0;
#pragma unroll
        for (int e = 0; e < NE; ++e) {
            const float v = part[0][t][e];
            if (e != i0 && v > v1) { v1 = v; i1 = e; }
        }
        // softmax over [v0, v1] with v0 >= v1 (overflow-safe)
        const float g1 = 1.0f / (1.0f + expf(v0 - v1));
        const float g0 = 1.0f - g1;
        const size_t gt = (size_t)(tok0 + t);
        out[gt * 2 + 0] = g0;
        out[gt * 2 + 1] = g1;
        out[IDX_OFF + gt * 2 + 0] = (float)i0;   // harness reads buffer as f32
        out[IDX_OFF + gt * 2 + 1] = (float)i1;
        out[TL_OFF + gt * 2 + 0] = v0;
        out[TL_OFF + gt * 2 + 1] = v1;
        atomicAdd(&sload[i0], g0);
        atomicAdd(&sload[i1], g1);
    }
    __syncthreads();
    if (tid < NE) atomicAdd(out + LOAD_OFF + tid, sload[tid]);
}

extern "C" void kernel_launch(void* const* d_in, const int* in_sizes, int n_in,
                              void* d_out, int out_size, void* d_ws, size_t ws_size,
                              hipStream_t stream)
{
    const float* x  = (const float*)d_in[0];
    const float* gw = (const float*)d_in[1];
    float* out = (float*)d_out;

    // load[] is accumulated with atomics; d_out is poisoned 0xAA pre-launch
    hipMemsetAsync(out + LOAD_OFF, 0, NE * sizeof(float), stream);

    router_kernel<<<dim3(M_TOTAL / TT), dim3(256), 0, stream>>>(x, gw, out);
}